// Round 3
// baseline (162.315 us; speedup 1.0000x reference)
//
#include <hip/hip_runtime.h>
#include <hip/hip_bf16.h>

// NLL of bivariate Gaussian, log-domain formulation.
// nll = z/(2(1-rho^2)) + log(2pi) + lsx + lsy + 0.5*log(1-rho^2)
// Clip: -log(max(pdf, 1e-10)) == fminf(nll, -log(1e-10)).
//
// R2: persistent grid-stride kernel. No LDS staging, no barrier between load
// and compute (R0 per-lane-AoS and R1 LDS-staged both sat at ~50us => pattern
// isn't the limiter; removing phase serialization + slashing VALU cost is the
// theory). 28 outstanding dword loads/wave; rcp-based tanh and divides.

#define THREADS 256
#define UNROLL 4

__device__ __forceinline__ float point_nll(float mux, float muy, float lsx,
                                           float lsy, float w, float y1, float y2) {
    const float LOG_2PI = 1.8378770664093453f;
    const float CLIP    = 23.025850929940457f; // -log(1e-10)
    float isx  = __expf(-lsx);
    float isy  = __expf(-lsy);
    float nx   = (y1 - mux) * isx;
    float ny   = (y2 - muy) * isy;
    // tanh(w) = 1 - 2/(exp(2w)+1); rcp-based (2% abs tolerance => plenty).
    float e2w  = __expf(2.0f * w);
    float corr = fmaf(-2.0f, __builtin_amdgcn_rcpf(e2w + 1.0f), 1.0f);
    float omr  = fmaf(-corr, corr, 1.0f);          // 1 - rho^2, exact-ish via fma
    float z    = fmaf(nx, nx, ny * ny) - 2.0f * corr * nx * ny;
    float nll  = fmaf(z, 0.5f * __builtin_amdgcn_rcpf(omr),
                      fmaf(0.5f, __logf(omr), lsx + lsy + LOG_2PI));
    return fminf(nll, CLIP); // inf/NaN from omr->0 underflow folds to CLIP, matching ref
}

__global__ __launch_bounds__(THREADS, 4) void nll_partial_kernel(
    const float* __restrict__ y, const float* __restrict__ o,
    float* __restrict__ partial, int N) {
    const int tid = threadIdx.x;
    const long long T = (long long)gridDim.x * THREADS; // total threads
    float acc = 0.0f;

    for (long long p0 = (long long)blockIdx.x * THREADS + tid; p0 < (long long)N;
         p0 += T * UNROLL) {
        float ov[UNROLL][5], yv1[UNROLL], yv2[UNROLL];
        bool ok[UNROLL];
        // Load phase: up to 7*UNROLL independent dword loads in flight.
#pragma unroll
        for (int j = 0; j < UNROLL; ++j) {
            long long p = p0 + (long long)j * T;
            ok[j] = (p < (long long)N);
            if (ok[j]) {
                const float* op = o + p * 5;
                const float* yp = y + p * 3;
#pragma unroll
                for (int c = 0; c < 5; ++c) ov[j][c] = op[c];
                yv1[j] = yp[1];
                yv2[j] = yp[2];
            }
        }
        // Compute phase.
#pragma unroll
        for (int j = 0; j < UNROLL; ++j) {
            if (ok[j])
                acc += point_nll(ov[j][0], ov[j][1], ov[j][2], ov[j][3], ov[j][4],
                                 yv1[j], yv2[j]);
        }
    }

    // wave-64 reduce, then cross-wave via LDS
#pragma unroll
    for (int off = 32; off > 0; off >>= 1) acc += __shfl_down(acc, off, 64);
    __shared__ float ws[THREADS / 64];
    if ((tid & 63) == 0) ws[tid >> 6] = acc;
    __syncthreads();
    if (tid == 0) {
        float s = 0.0f;
#pragma unroll
        for (int i = 0; i < THREADS / 64; ++i) s += ws[i];
        partial[blockIdx.x] = s;
    }
}

__global__ __launch_bounds__(THREADS) void nll_final_kernel(
    const float* __restrict__ partial, int nparts, float* __restrict__ out,
    float inv_p) {
    float acc = 0.0f;
    for (int i = threadIdx.x; i < nparts; i += THREADS) acc += partial[i];
#pragma unroll
    for (int off = 32; off > 0; off >>= 1) acc += __shfl_down(acc, off, 64);
    __shared__ float ws[THREADS / 64];
    if ((threadIdx.x & 63) == 0) ws[threadIdx.x >> 6] = acc;
    __syncthreads();
    if (threadIdx.x == 0) {
        float s = 0.0f;
#pragma unroll
        for (int i = 0; i < THREADS / 64; ++i) s += ws[i];
        out[0] = s * inv_p;
    }
}

extern "C" void kernel_launch(void* const* d_in, const int* in_sizes, int n_in,
                              void* d_out, int out_size, void* d_ws, size_t ws_size,
                              hipStream_t stream) {
    const float* y = (const float*)d_in[0]; // (B,T,P,3)
    const float* o = (const float*)d_in[1]; // (B,T,P,5)
    int N = in_sizes[1] / 5;                // B*T*P points
    int max_blocks = (N + THREADS * UNROLL - 1) / (THREADS * UNROLL);
    int blocks = max_blocks < 2048 ? max_blocks : 2048; // 8 blocks/CU persistent
    if (blocks < 1) blocks = 1;

    float* partial = (float*)d_ws;
    nll_partial_kernel<<<blocks, THREADS, 0, stream>>>(y, o, partial, N);
    // P = 512 (pdf.shape[2] in the reference); 1/512 is exact in fp32.
    nll_final_kernel<<<1, THREADS, 0, stream>>>(partial, blocks, (float*)d_out,
                                                1.0f / 512.0f);
}

// Round 4
// 151.789 us; speedup vs baseline: 1.0693x; 1.0693x over previous
//
#include <hip/hip_runtime.h>
#include <hip/hip_bf16.h>

// NLL of bivariate Gaussian, log-domain formulation.
// nll = z/(2(1-rho^2)) + log(2pi) + lsx + lsy + 0.5*log(1-rho^2)
// Clip: -log(max(pdf, 1e-10)) == fminf(nll, -log(1e-10)).
//
// R4: R0/R1/R2 (three different structures) all pinned at ~50us with
// FETCH_SIZE~0 => inputs are LLC-resident and we're L1-miss-concurrency
// bound (~34 lines/CU by Little's law at ~500cyc LLC latency). This round:
// non-temporal (L1-bypass) staging loads to escape the TCP MSHR cap.

#define THREADS 256
#define PPT 4                // points per thread
#define TILE (THREADS * PPT) // 1024 points per block

typedef float v4 __attribute__((ext_vector_type(4)));

__device__ __forceinline__ float point_nll(float mux, float muy, float lsx,
                                           float lsy, float w, float y1, float y2) {
    const float LOG_2PI = 1.8378770664093453f;
    const float CLIP    = 23.025850929940457f; // -log(1e-10)
    float isx  = __expf(-lsx);
    float isy  = __expf(-lsy);
    float nx   = (y1 - mux) * isx;
    float ny   = (y2 - muy) * isy;
    // tanh(w) = 1 - 2/(exp(2w)+1); rcp-based (2% abs tolerance => plenty).
    float e2w  = __expf(2.0f * w);
    float corr = fmaf(-2.0f, __builtin_amdgcn_rcpf(e2w + 1.0f), 1.0f);
    float omr  = fmaf(-corr, corr, 1.0f);          // 1 - rho^2
    float z    = fmaf(nx, nx, ny * ny) - 2.0f * corr * nx * ny;
    float nll  = fmaf(z, 0.5f * __builtin_amdgcn_rcpf(omr),
                      fmaf(0.5f, __logf(omr), lsx + lsy + LOG_2PI));
    return fminf(nll, CLIP); // inf/NaN (omr->0) folds to CLIP, matching ref
}

__global__ __launch_bounds__(THREADS) void nll_partial_kernel(
    const float* __restrict__ y, const float* __restrict__ o,
    float* __restrict__ partial, int N) {
    __shared__ v4 lds_o[5 * THREADS]; // 20 KB
    __shared__ v4 lds_y[3 * THREADS]; // 12 KB

    const int tid = threadIdx.x;
    const long long base_pt = (long long)blockIdx.x * TILE;
    float acc = 0.0f;

    if (base_pt + TILE <= (long long)N) {
        // Coalesced, NON-TEMPORAL staging: bypass L1, go straight to L2/fabric.
        const v4* o4 = (const v4*)o + base_pt * 5 / 4; // tile*1280 floats
        const v4* y4 = (const v4*)y + base_pt * 3 / 4; // tile*768 floats
#pragma unroll
        for (int k = 0; k < 5; ++k)
            lds_o[k * THREADS + tid] = __builtin_nontemporal_load(o4 + k * THREADS + tid);
#pragma unroll
        for (int k = 0; k < 3; ++k)
            lds_y[k * THREADS + tid] = __builtin_nontemporal_load(y4 + k * THREADS + tid);
        __syncthreads();

        const float* fo = (const float*)lds_o + tid * (PPT * 5);
        const float* fy = (const float*)lds_y + tid * (PPT * 3);
#pragma unroll
        for (int j = 0; j < PPT; ++j) {
            acc += point_nll(fo[5 * j + 0], fo[5 * j + 1], fo[5 * j + 2],
                             fo[5 * j + 3], fo[5 * j + 4],
                             fy[3 * j + 1], fy[3 * j + 2]);
        }
    } else {
        // Tail tile (not hit for N = 4,194,304): guarded scalar path.
        long long i0 = base_pt + (long long)tid * PPT;
        for (int j = 0; j < PPT; ++j) {
            long long i = i0 + j;
            if (i < (long long)N)
                acc += point_nll(o[i * 5 + 0], o[i * 5 + 1], o[i * 5 + 2],
                                 o[i * 5 + 3], o[i * 5 + 4],
                                 y[i * 3 + 1], y[i * 3 + 2]);
        }
    }

    // wave-64 reduce, then cross-wave via LDS
#pragma unroll
    for (int off = 32; off > 0; off >>= 1) acc += __shfl_down(acc, off, 64);
    __shared__ float ws[THREADS / 64];
    if ((tid & 63) == 0) ws[tid >> 6] = acc;
    __syncthreads();
    if (tid == 0) {
        float s = 0.0f;
#pragma unroll
        for (int i = 0; i < THREADS / 64; ++i) s += ws[i];
        partial[blockIdx.x] = s;
    }
}

__global__ __launch_bounds__(THREADS) void nll_final_kernel(
    const float* __restrict__ partial, int nparts, float* __restrict__ out,
    float inv_p) {
    float acc = 0.0f;
    for (int i = threadIdx.x; i < nparts; i += THREADS) acc += partial[i];
#pragma unroll
    for (int off = 32; off > 0; off >>= 1) acc += __shfl_down(acc, off, 64);
    __shared__ float ws[THREADS / 64];
    if ((threadIdx.x & 63) == 0) ws[threadIdx.x >> 6] = acc;
    __syncthreads();
    if (threadIdx.x == 0) {
        float s = 0.0f;
#pragma unroll
        for (int i = 0; i < THREADS / 64; ++i) s += ws[i];
        out[0] = s * inv_p;
    }
}

extern "C" void kernel_launch(void* const* d_in, const int* in_sizes, int n_in,
                              void* d_out, int out_size, void* d_ws, size_t ws_size,
                              hipStream_t stream) {
    const float* y = (const float*)d_in[0]; // (B,T,P,3)
    const float* o = (const float*)d_in[1]; // (B,T,P,5)
    int N = in_sizes[1] / 5;                // B*T*P points
    int blocks = (N + TILE - 1) / TILE;     // 4096 for the reference shape

    float* partial = (float*)d_ws;
    nll_partial_kernel<<<blocks, THREADS, 0, stream>>>(y, o, partial, N);
    // P = 512 (pdf.shape[2] in the reference); 1/512 is exact in fp32.
    nll_final_kernel<<<1, THREADS, 0, stream>>>(partial, blocks, (float*)d_out,
                                                1.0f / 512.0f);
}

// Round 5
// 150.660 us; speedup vs baseline: 1.0774x; 1.0075x over previous
//
#include <hip/hip_runtime.h>
#include <hip/hip_bf16.h>

// NLL of bivariate Gaussian, log-domain formulation.
// nll = z/(2(1-rho^2)) + log(2pi) + lsx + lsy + 0.5*log(1-rho^2)
// Clip: -log(max(pdf, 1e-10)) == fminf(nll, -log(1e-10)).
//
// R5: persistent grid + register prefetch of next tile + wave-private LDS
// transpose (NO __syncthreads in hot loop) + nt unit-stride b128 loads.
// R4 (one-shot blocks, barrier) => vmcnt(0) drain each tile, ~3.35 TB/s.
// Register prefetch lets the compiler emit partial vmcnt waits so next
// tile's loads stay in flight across current tile's LDS+compute.

#define THREADS 256
#define PPT 4                // points per thread
#define TILE (THREADS * PPT) // 1024 points per block-tile
#define MAXBLOCKS 1024       // 4 blocks/CU (32 KB LDS each)

typedef float v4 __attribute__((ext_vector_type(4)));

__device__ __forceinline__ float point_nll(float mux, float muy, float lsx,
                                           float lsy, float w, float y1, float y2) {
    const float LOG_2PI = 1.8378770664093453f;
    const float CLIP    = 23.025850929940457f; // -log(1e-10)
    float isx  = __expf(-lsx);
    float isy  = __expf(-lsy);
    float nx   = (y1 - mux) * isx;
    float ny   = (y2 - muy) * isy;
    // tanh(w) = 1 - 2/(exp(2w)+1); rcp-based (2% abs tolerance => plenty).
    float e2w  = __expf(2.0f * w);
    float corr = fmaf(-2.0f, __builtin_amdgcn_rcpf(e2w + 1.0f), 1.0f);
    float omr  = fmaf(-corr, corr, 1.0f);          // 1 - rho^2
    float z    = fmaf(nx, nx, ny * ny) - 2.0f * corr * nx * ny;
    float nll  = fmaf(z, 0.5f * __builtin_amdgcn_rcpf(omr),
                      fmaf(0.5f, __logf(omr), lsx + lsy + LOG_2PI));
    return fminf(nll, CLIP); // inf/NaN (omr->0) folds to CLIP, matching ref
}

__global__ __launch_bounds__(THREADS) void nll_partial_kernel(
    const float* __restrict__ y, const float* __restrict__ o,
    float* __restrict__ partial, int N) {
    // Wave-private staging: 8 KB/wave (o: 320 float4, y: 192 float4).
    __shared__ v4 lds[4][512]; // 32 KB total
    const int tid  = threadIdx.x;
    const int wave = tid >> 6;
    const int lane = tid & 63;
    v4* wbuf = lds[wave];
    const v4* o4 = (const v4*)o;
    const v4* y4 = (const v4*)y;

    const int ntiles = (N + TILE - 1) / TILE;
    const int step   = gridDim.x;
    float acc = 0.0f;

    int  t        = blockIdx.x;
    bool valid    = t < ntiles;
    bool cur_full = false;
    v4 ro[5] = {}, ry[3] = {};
    if (valid) {
        cur_full = (long long)(t + 1) * TILE <= (long long)N;
        if (cur_full) {
            long long ob = (long long)t * 1280 + wave * 320 + lane;
            long long yb = (long long)t * 768  + wave * 192 + lane;
#pragma unroll
            for (int k = 0; k < 5; ++k) ro[k] = __builtin_nontemporal_load(o4 + ob + k * 64);
#pragma unroll
            for (int k = 0; k < 3; ++k) ry[k] = __builtin_nontemporal_load(y4 + yb + k * 64);
        }
    }

    while (valid) {
        const int  tn     = t + step;
        const bool nvalid = tn < ntiles;
        const bool nfull  = nvalid && (long long)(tn + 1) * TILE <= (long long)N;
        v4 po[5] = {}, py[3] = {};
        if (nfull) { // prefetch next tile: stays in flight during compute below
            long long ob = (long long)tn * 1280 + wave * 320 + lane;
            long long yb = (long long)tn * 768  + wave * 192 + lane;
#pragma unroll
            for (int k = 0; k < 5; ++k) po[k] = __builtin_nontemporal_load(o4 + ob + k * 64);
#pragma unroll
            for (int k = 0; k < 3; ++k) py[k] = __builtin_nontemporal_load(y4 + yb + k * 64);
        }

        if (cur_full) {
            // Wave-private LDS transpose: no barrier, only lgkmcnt ordering.
#pragma unroll
            for (int k = 0; k < 5; ++k) wbuf[k * 64 + lane] = ro[k];
#pragma unroll
            for (int k = 0; k < 3; ++k) wbuf[320 + k * 64 + lane] = ry[k];
            const float* fo = (const float*)wbuf + lane * (PPT * 5);
            const float* fy = (const float*)(wbuf + 320) + lane * (PPT * 3);
#pragma unroll
            for (int j = 0; j < PPT; ++j) {
                acc += point_nll(fo[5 * j + 0], fo[5 * j + 1], fo[5 * j + 2],
                                 fo[5 * j + 3], fo[5 * j + 4],
                                 fy[3 * j + 1], fy[3 * j + 2]);
            }
        } else {
            // Partial tail tile: guarded scalar path (cold for N % TILE == 0).
            long long base = (long long)t * TILE + wave * 256 + (long long)lane * PPT;
            for (int j = 0; j < PPT; ++j) {
                long long i = base + j;
                if (i < (long long)N)
                    acc += point_nll(o[i * 5 + 0], o[i * 5 + 1], o[i * 5 + 2],
                                     o[i * 5 + 3], o[i * 5 + 4],
                                     y[i * 3 + 1], y[i * 3 + 2]);
            }
        }

#pragma unroll
        for (int k = 0; k < 5; ++k) ro[k] = po[k];
#pragma unroll
        for (int k = 0; k < 3; ++k) ry[k] = py[k];
        cur_full = nfull;
        t = tn;
        valid = nvalid;
    }

    // wave-64 reduce, then cross-wave via LDS (single barrier at kernel end)
#pragma unroll
    for (int off = 32; off > 0; off >>= 1) acc += __shfl_down(acc, off, 64);
    __shared__ float ws[THREADS / 64];
    if (lane == 0) ws[wave] = acc;
    __syncthreads();
    if (tid == 0) {
        float s = 0.0f;
#pragma unroll
        for (int i = 0; i < THREADS / 64; ++i) s += ws[i];
        partial[blockIdx.x] = s;
    }
}

__global__ __launch_bounds__(THREADS) void nll_final_kernel(
    const float* __restrict__ partial, int nparts, float* __restrict__ out,
    float inv_p) {
    float acc = 0.0f;
    for (int i = threadIdx.x; i < nparts; i += THREADS) acc += partial[i];
#pragma unroll
    for (int off = 32; off > 0; off >>= 1) acc += __shfl_down(acc, off, 64);
    __shared__ float ws[THREADS / 64];
    if ((threadIdx.x & 63) == 0) ws[threadIdx.x >> 6] = acc;
    __syncthreads();
    if (threadIdx.x == 0) {
        float s = 0.0f;
#pragma unroll
        for (int i = 0; i < THREADS / 64; ++i) s += ws[i];
        out[0] = s * inv_p;
    }
}

extern "C" void kernel_launch(void* const* d_in, const int* in_sizes, int n_in,
                              void* d_out, int out_size, void* d_ws, size_t ws_size,
                              hipStream_t stream) {
    const float* y = (const float*)d_in[0]; // (B,T,P,3)
    const float* o = (const float*)d_in[1]; // (B,T,P,5)
    int N = in_sizes[1] / 5;                // B*T*P points
    int ntiles = (N + TILE - 1) / TILE;     // 4096 for the reference shape
    int blocks = ntiles < MAXBLOCKS ? ntiles : MAXBLOCKS;
    if (blocks < 1) blocks = 1;

    float* partial = (float*)d_ws;
    nll_partial_kernel<<<blocks, THREADS, 0, stream>>>(y, o, partial, N);
    // P = 512 (pdf.shape[2] in the reference); 1/512 is exact in fp32.
    nll_final_kernel<<<1, THREADS, 0, stream>>>(partial, blocks, (float*)d_out,
                                                1.0f / 512.0f);
}

// Round 6
// 149.658 us; speedup vs baseline: 1.0846x; 1.0067x over previous
//
#include <hip/hip_runtime.h>
#include <hip/hip_bf16.h>

// NLL of bivariate Gaussian, log-domain formulation.
// nll = z/(2(1-rho^2)) + log(2pi) + lsx + lsy + 0.5*log(1-rho^2)
// Clip: -log(max(pdf, 1e-10)) == fminf(nll, -log(1e-10)).
//
// R6: global_load_lds DMA streaming. R0-R5 establish a ~3.4 TB/s cap on the
// VGPR-return read path regardless of structure (pattern, MLP, barriers all
// ruled out). This is the only read path that skips the VGPR return: TA->LDS
// direct, vmcnt-tracked with no register dep, so manual s_waitcnt vmcnt(8)
// survives compilation (no compiler-inserted vmcnt(0) possible). Wave-private
// double buffer, 8 DMA loads/tile in flight across the previous tile's compute.

#define THREADS 256
#define PPT 4                // points per thread
#define TILE (THREADS * PPT) // 1024 points per block-tile; 256 per wave
#define MAXBLOCKS 512        // 64 KB LDS/block -> 2 blocks/CU

typedef float v4 __attribute__((ext_vector_type(4)));
typedef __attribute__((address_space(3))) v4 as3_v4;
typedef const __attribute__((address_space(1))) v4 as1_v4;

__device__ __forceinline__ float point_nll(float mux, float muy, float lsx,
                                           float lsy, float w, float y1, float y2) {
    const float LOG_2PI = 1.8378770664093453f;
    const float CLIP    = 23.025850929940457f; // -log(1e-10)
    float isx  = __expf(-lsx);
    float isy  = __expf(-lsy);
    float nx   = (y1 - mux) * isx;
    float ny   = (y2 - muy) * isy;
    // tanh(w) = 1 - 2/(exp(2w)+1); rcp-based (2% abs tolerance => plenty).
    float e2w  = __expf(2.0f * w);
    float corr = fmaf(-2.0f, __builtin_amdgcn_rcpf(e2w + 1.0f), 1.0f);
    float omr  = fmaf(-corr, corr, 1.0f);          // 1 - rho^2
    float z    = fmaf(nx, nx, ny * ny) - 2.0f * corr * nx * ny;
    float nll  = fmaf(z, 0.5f * __builtin_amdgcn_rcpf(omr),
                      fmaf(0.5f, __logf(omr), lsx + lsy + LOG_2PI));
    return fminf(nll, CLIP); // inf/NaN (omr->0) folds to CLIP, matching ref
}

__global__ __launch_bounds__(THREADS) void nll_partial_kernel(
    const float* __restrict__ y, const float* __restrict__ o,
    float* __restrict__ partial, int N) {
    // Per-wave double buffer: [o: 320 v4][y: 192 v4] = 8 KB per buffer.
    __shared__ v4 lds[4][2][512]; // 64 KB
    const int tid  = threadIdx.x;
    const int wave = tid >> 6;
    const int lane = tid & 63;
    const v4* o4 = (const v4*)o;
    const v4* y4 = (const v4*)y;

    const int nfull = N / TILE; // full tiles only in the DMA pipeline
    const int step  = gridDim.x;
    float acc = 0.0f;

    // Issue DMA for one tile's wave-chunk into buffer b (8x dwordx4/wave).
    // LDS dest is wave-uniform base; HW deposits at base + lane*16 == layout.
    auto issue = [&](int t, int b) {
        const v4* gob = o4 + (long long)t * 1280 + wave * 320 + lane;
        const v4* gyb = y4 + (long long)t * 768  + wave * 192 + lane;
        v4* ob = &lds[wave][b][0];
        v4* yb = &lds[wave][b][320];
#pragma unroll
        for (int k = 0; k < 5; ++k)
            __builtin_amdgcn_global_load_lds((as1_v4*)(gob + k * 64),
                                             (as3_v4*)(ob + k * 64), 16, 0, 2 /*NT*/);
#pragma unroll
        for (int k = 0; k < 3; ++k)
            __builtin_amdgcn_global_load_lds((as1_v4*)(gyb + k * 64),
                                             (as3_v4*)(yb + k * 64), 16, 0, 2 /*NT*/);
    };

    int t = blockIdx.x;
    int p = 0;
    if (t < nfull) issue(t, p);
    while (t < nfull) {
        const int  tn  = t + step;
        const bool pre = tn < nfull;
        if (pre) issue(tn, p ^ 1); // next tile's 8 loads go in flight now

        // Wait only for the CURRENT tile's 8 loads (prefetch stays in flight).
        if (pre) __builtin_amdgcn_s_waitcnt(0x0F78); // vmcnt(8), lgkm/exp no-wait
        else     __builtin_amdgcn_s_waitcnt(0x0F70); // vmcnt(0)
        asm volatile("" ::: "memory"); // pin LDS reads below the waitcnt

        const float* fo = (const float*)&lds[wave][p][0]   + lane * (PPT * 5);
        const float* fy = (const float*)&lds[wave][p][320] + lane * (PPT * 3);
#pragma unroll
        for (int j = 0; j < PPT; ++j) {
            acc += point_nll(fo[5 * j + 0], fo[5 * j + 1], fo[5 * j + 2],
                             fo[5 * j + 3], fo[5 * j + 4],
                             fy[3 * j + 1], fy[3 * j + 2]);
        }
        p ^= 1;
        t = tn;
    }

    // Tail points (N % TILE; zero for the reference shape): direct loads.
    long long gid = (long long)blockIdx.x * THREADS + tid;
    for (long long i = (long long)nfull * TILE + gid; i < (long long)N;
         i += (long long)step * THREADS) {
        acc += point_nll(o[i * 5 + 0], o[i * 5 + 1], o[i * 5 + 2],
                         o[i * 5 + 3], o[i * 5 + 4],
                         y[i * 3 + 1], y[i * 3 + 2]);
    }

    // wave-64 reduce, then cross-wave via LDS
#pragma unroll
    for (int off = 32; off > 0; off >>= 1) acc += __shfl_down(acc, off, 64);
    __shared__ float ws[THREADS / 64];
    if (lane == 0) ws[wave] = acc;
    __syncthreads();
    if (tid == 0) {
        float s = 0.0f;
#pragma unroll
        for (int i = 0; i < THREADS / 64; ++i) s += ws[i];
        partial[blockIdx.x] = s;
    }
}

__global__ __launch_bounds__(THREADS) void nll_final_kernel(
    const float* __restrict__ partial, int nparts, float* __restrict__ out,
    float inv_p) {
    float acc = 0.0f;
    for (int i = threadIdx.x; i < nparts; i += THREADS) acc += partial[i];
#pragma unroll
    for (int off = 32; off > 0; off >>= 1) acc += __shfl_down(acc, off, 64);
    __shared__ float ws[THREADS / 64];
    if ((threadIdx.x & 63) == 0) ws[threadIdx.x >> 6] = acc;
    __syncthreads();
    if (threadIdx.x == 0) {
        float s = 0.0f;
#pragma unroll
        for (int i = 0; i < THREADS / 64; ++i) s += ws[i];
        out[0] = s * inv_p;
    }
}

extern "C" void kernel_launch(void* const* d_in, const int* in_sizes, int n_in,
                              void* d_out, int out_size, void* d_ws, size_t ws_size,
                              hipStream_t stream) {
    const float* y = (const float*)d_in[0]; // (B,T,P,3)
    const float* o = (const float*)d_in[1]; // (B,T,P,5)
    int N = in_sizes[1] / 5;                // B*T*P points
    int ntiles = (N + TILE - 1) / TILE;     // 4096 for the reference shape
    int blocks = ntiles < MAXBLOCKS ? ntiles : MAXBLOCKS;
    if (blocks < 1) blocks = 1;

    float* partial = (float*)d_ws;
    nll_partial_kernel<<<blocks, THREADS, 0, stream>>>(y, o, partial, N);
    // P = 512 (pdf.shape[2] in the reference); 1/512 is exact in fp32.
    nll_final_kernel<<<1, THREADS, 0, stream>>>(partial, blocks, (float*)d_out,
                                                1.0f / 512.0f);
}